// Round 2
// baseline (296.236 us; speedup 1.0000x reference)
//
#include <hip/hip_runtime.h>
#include <math.h>

// Model: review-based recommender. ALL float tensors are fp32 (per reference).
// Shapes: VOCAB=20000, D=100, H=100, K=3, N_U=N_I=256, R=8, S=52, Sp=50, E=20000.
// Outputs (fp32, flat): pred_r[20000] @0, pred_c[20000] @20000,
//                       z_u[256*8*50] @40000, z_i[102400] @142400.

__device__ __forceinline__ float sigmoidf_(float x) { return 1.f / (1.f + expf(-x)); }

// ---------------------------------------------------------------------------
// K0: transpose conv_w [h=100][kk=300] -> Wt [kk=300][h=100] (fp32) for
// coalesced chunk staging in k_branch.
__global__ void k_wt(const float* __restrict__ conv_w, float* __restrict__ Wt) {
    int idx = blockIdx.x * 256 + threadIdx.x;
    if (idx >= 30000) return;
    int kk = idx / 100, h = idx - kk * 100;
    Wt[idx] = conv_w[h * 300 + kk];
}

// ---------------------------------------------------------------------------
// K1: per (branch, b, r) instance: emb gather -> fp32 conv -> c -> z, P, zdot, Pdot.
// One block = one instance. 250 active compute threads, tile 5 s' x 4 h each.
__launch_bounds__(256)
__global__ void k_branch(const int* __restrict__ u_rev, const int* __restrict__ i_rev,
                         const float* __restrict__ emb, const float* __restrict__ Wt,
                         const float* __restrict__ conv_b, const float* __restrict__ fc_w_w,
                         const float* __restrict__ fc_w_b, const float* __restrict__ fc_w2_w,
                         const float* __restrict__ fc_w2_b, const float* __restrict__ h_r_w,
                         const float* __restrict__ h_c_w,
                         float* __restrict__ Pbuf, float* __restrict__ zdot,
                         float* __restrict__ Pdot, float* __restrict__ z_out) {
    __shared__ __align__(16) char smem[46336];
    float* s_x   = (float*)smem;                 // [5200] embflat fp32 (X[s][d], s<52)
    float* s_c   = (float*)smem;                 // [50][104] fp32, overlays s_x after conv
    float* s_w   = (float*)(smem + 20800);       // [60][100] W chunk
    int*   s_tok = (int*)(smem + 44800);         // [52]
    float* s_z   = (float*)(smem + 45056);       // [50]
    float* s_max = (float*)(smem + 45312);       // [100]
    float* s_P   = (float*)(smem + 45760);       // [100]

    const int bid = blockIdx.x;
    const int branch = bid >> 11, inst = bid & 2047;
    const int tid = threadIdx.x, lane = tid & 63, wave = tid >> 6;
    const int* rev = branch ? i_rev : u_rev;

    if (tid < 52) s_tok[tid] = rev[inst * 52 + tid];
    __syncthreads();

    // embedding gather: s_x[s*100+d] = emb[tok[s]*100+d]
    for (int idx = tid; idx < 5200; idx += 256) {
        int s = idx / 100, d = idx - s * 100;
        s_x[idx] = emb[s_tok[s] * 100 + d];
    }

    const bool active = tid < 250;
    const int hg = tid % 25, sg = tid / 25;      // sg in 0..9 for active threads
    const int h4 = hg * 4, s5 = sg * 5;
    float acc[5][4];
#pragma unroll
    for (int i = 0; i < 5; i++)
#pragma unroll
        for (int jj = 0; jj < 4; jj++) acc[i][jj] = 0.f;

    for (int ck = 0; ck < 5; ck++) {
        __syncthreads();                         // prior chunk reads done (+ gather, ck=0)
        {   // stage W chunk: Wt rows ck*60 .. ck*60+59 -> s_w (6000 floats)
            const float4* src = (const float4*)(Wt + ck * 6000);
            float4* dst = (float4*)s_w;
            for (int i = tid; i < 1500; i += 256) dst[i] = src[i];
        }
        __syncthreads();
        if (active) {
            const int kk0 = ck * 60;
            for (int j = 0; j < 60; j += 4) {
                float4 xa[5], wb[4];
#pragma unroll
                for (int i = 0; i < 5; i++)
                    xa[i] = *(const float4*)&s_x[(s5 + i) * 100 + kk0 + j];
#pragma unroll
                for (int jj = 0; jj < 4; jj++)
                    wb[jj] = *(const float4*)&s_w[(j + jj) * 100 + h4];
#pragma unroll
                for (int i = 0; i < 5; i++) {
                    const float* xs = (const float*)&xa[i];
#pragma unroll
                    for (int jj = 0; jj < 4; jj++) {
                        float x = xs[jj];
                        acc[i][0] += x * wb[jj].x;
                        acc[i][1] += x * wb[jj].y;
                        acc[i][2] += x * wb[jj].z;
                        acc[i][3] += x * wb[jj].w;
                    }
                }
            }
        }
    }
    __syncthreads();                             // all s_x/s_w reads done; reuse as s_c

    // c = relu(conv + bias) into s_c[50][104]
    if (active) {
        float cb[4];
#pragma unroll
        for (int jj = 0; jj < 4; jj++) cb[jj] = conv_b[h4 + jj];
#pragma unroll
        for (int i = 0; i < 5; i++) {
            int sp = s5 + i;
#pragma unroll
            for (int jj = 0; jj < 4; jj++) {
                float v = acc[i][jj] + cb[jj];
                s_c[sp * 104 + h4 + jj] = v > 0.f ? v : 0.f;
            }
        }
    }
    __syncthreads();

    // rho / z per position (straight-through round => z = rint(sigmoid))
    if (tid < 200) {
        int pp = tid >> 2, q = tid & 3;
        float part = 0.f;
        for (int h = q * 25; h < q * 25 + 25; h++) part += s_c[pp * 104 + h] * fc_w_w[h];
        part += __shfl_xor(part, 1, 64);
        part += __shfl_xor(part, 2, 64);
        if (q == 0) {
            float z = rintf(sigmoidf_(part + fc_w_b[0]));
            s_z[pp] = z;
            z_out[branch * 102400 + inst * 50 + pp] = z;
        }
    }
    __syncthreads();

    // column max over positions (c >= 0 post-relu)
    if (tid < 100) {
        float m = 0.f;
        for (int pr = 0; pr < 50; pr++) m = fmaxf(m, s_c[pr * 104 + tid]);
        s_max[tid] = m;
    }
    __syncthreads();

    // P[dd] = fc_w2_b[dd] + sum_h cmax[h] * fc_w2_w[dd*100+h]
    for (int dd = tid >> 2; dd < 100; dd += 64) {
        int q = tid & 3;
        float part = 0.f;
        for (int h = q * 25; h < q * 25 + 25; h++) part += s_max[h] * fc_w2_w[dd * 100 + h];
        part += __shfl_xor(part, 1, 64);
        part += __shfl_xor(part, 2, 64);
        if (q == 0) {
            float Pv = part + fc_w2_b[dd];
            Pbuf[(branch * 2048 + inst) * 100 + dd] = Pv;
            s_P[dd] = Pv;
        }
    }
    __syncthreads();

    // zdot = z . h_r_w[branch half], Pdot = P . h_c_w[branch half]
    if (wave == 0) {
        float v = (lane < 50) ? s_z[lane] * h_r_w[branch * 50 + lane] : 0.f;
        for (int s = 1; s < 64; s <<= 1) v += __shfl_xor(v, s, 64);
        if (lane == 0) zdot[branch * 2048 + inst] = v;
    } else if (wave == 1) {
        float v = 0.f;
        if (lane < 50) v = s_P[lane] * h_c_w[branch * 100 + lane]
                         + s_P[lane + 50] * h_c_w[branch * 100 + lane + 50];
        for (int s = 1; s < 64; s <<= 1) v += __shfl_xor(v, s, 64);
        if (lane == 0) Pdot[branch * 2048 + inst] = v;
    }
}

// ---------------------------------------------------------------------------
// K2: Psum[br][b][d] = sum_r Pbuf[br][b*8+r][d]
__global__ void k_psum(const float* __restrict__ Pbuf, float* __restrict__ Psum) {
    int idx = blockIdx.x * 256 + threadIdx.x;
    if (idx >= 51200) return;
    int br = idx / 25600, rem = idx - br * 25600;
    int b = rem / 100, d = rem - b * 100;
    float s = 0.f;
    for (int r = 0; r < 8; r++) s += Pbuf[(br * 2048 + b * 8 + r) * 100 + d];
    Psum[idx] = s;
}

// ---------------------------------------------------------------------------
// K3: per-edge. rho_u[a]=sig(Pu[a].PsumI), rho_v[v]=sig(Pi[v].PsumU);
// pred_r = sum_a rho_u[a]*zdot_u[a] + sum_v rho_v[v]*zdot_i[v] + biases;
// pred_c analogous with Pdot. One wave per edge, 16 groups x 4 lanes.
__launch_bounds__(256)
__global__ void k_edge(const int* __restrict__ uid, const int* __restrict__ iid,
                       const float* __restrict__ Pbuf, const float* __restrict__ Psum,
                       const float* __restrict__ zdot, const float* __restrict__ Pdot,
                       const float* __restrict__ user_bias, const float* __restrict__ item_bias,
                       const float* __restrict__ global_bias, float* __restrict__ out) {
    int wave = threadIdx.x >> 6, lane = threadIdx.x & 63;
    int e = blockIdx.x * 4 + wave;
    int u = uid[e], i = iid[e];
    int g = lane >> 2, q = lane & 3;
    const float* prow; const float* psum; float wr, wc;
    if (g < 8) {
        prow = Pbuf + (u * 8 + g) * 100;
        psum = Psum + 25600 + i * 100;
        wr = zdot[u * 8 + g]; wc = Pdot[u * 8 + g];
    } else {
        prow = Pbuf + (2048 + i * 8 + (g - 8)) * 100;
        psum = Psum + u * 100;
        wr = zdot[2048 + i * 8 + (g - 8)]; wc = Pdot[2048 + i * 8 + (g - 8)];
    }
    float part = 0.f;
    for (int d = q * 25; d < q * 25 + 25; d++) part += prow[d] * psum[d];
    part += __shfl_xor(part, 1, 64);
    part += __shfl_xor(part, 2, 64);
    float sg = sigmoidf_(part);
    float cr = (q == 0) ? sg * wr : 0.f;
    float cc = (q == 0) ? sg * wc : 0.f;
    for (int s = 4; s < 64; s <<= 1) { cr += __shfl_xor(cr, s, 64); cc += __shfl_xor(cc, s, 64); }
    if (lane == 0) {
        out[e] = cr + user_bias[u] + item_bias[i] + global_bias[0];
        out[20000 + e] = cc;
    }
}

// ---------------------------------------------------------------------------
extern "C" void kernel_launch(void* const* d_in, const int* in_sizes, int n_in,
                              void* d_out, int out_size, void* d_ws, size_t ws_size,
                              hipStream_t stream) {
    const int*   u_rev    = (const int*)d_in[0];
    const int*   i_rev    = (const int*)d_in[1];
    const int*   uid      = (const int*)d_in[2];
    const int*   iid      = (const int*)d_in[3];
    const float* emb      = (const float*)d_in[4];
    const float* conv_w   = (const float*)d_in[5];
    const float* conv_b   = (const float*)d_in[6];
    const float* fc_w_w   = (const float*)d_in[7];
    const float* fc_w_b   = (const float*)d_in[8];
    const float* fc_w2_w  = (const float*)d_in[9];
    const float* fc_w2_b  = (const float*)d_in[10];
    const float* h_r_w    = (const float*)d_in[11];
    const float* h_c_w    = (const float*)d_in[12];
    const float* user_b   = (const float*)d_in[13];
    const float* item_b   = (const float*)d_in[14];
    const float* global_b = (const float*)d_in[15];
    float* out = (float*)d_out;

    float* Pbuf = (float*)d_ws;              // [2][2048][100]
    float* Psum = Pbuf + 409600;             // [2][256][100]
    float* zdotb = Psum + 51200;             // [2][2048]
    float* Pdotb = zdotb + 4096;             // [2][2048]
    float* Wt    = Pdotb + 4096;             // [300][100]

    hipLaunchKernelGGL(k_wt, dim3(118), dim3(256), 0, stream, conv_w, Wt);
    hipLaunchKernelGGL(k_branch, dim3(4096), dim3(256), 0, stream,
                       u_rev, i_rev, emb, Wt, conv_b, fc_w_w, fc_w_b,
                       fc_w2_w, fc_w2_b, h_r_w, h_c_w,
                       Pbuf, zdotb, Pdotb, out + 40000);
    hipLaunchKernelGGL(k_psum, dim3(200), dim3(256), 0, stream, Pbuf, Psum);
    hipLaunchKernelGGL(k_edge, dim3(5000), dim3(256), 0, stream,
                       uid, iid, Pbuf, Psum, zdotb, Pdotb,
                       user_b, item_b, global_b, out);
}